// Round 1
// baseline (13517.523 us; speedup 1.0000x reference)
//
#include <hip/hip_runtime.h>

#define Bn 32
#define Tn 2048
#define Hn 256
#define DEPTHn 4

// ---------------------------------------------------------------------------
// Phase A: Z[b,t,:] = in[b,t,:] @ Wx + bias      (parallel over all B*T rows)
// in row address: in + b*in_bstride + t*Hn
// Grid: (B*T/64) workgroups, 256 threads. Each wg computes a 64-row tile.
// ---------------------------------------------------------------------------
__global__ __launch_bounds__(256, 1) void gemm_xw(
    const float* __restrict__ in, long in_bstride,
    const float* __restrict__ Wx, const float* __restrict__ bias,
    float* __restrict__ Z)
{
    __shared__ __align__(16) float a_lds[64][256];

    const int tid = threadIdx.x;
    const int row0 = blockIdx.x * 64;   // global row in [0, B*T)

    // Load A tile (64 rows x 256 cols fp32 = 64 KB) coalesced as float4.
    #pragma unroll
    for (int q = 0; q < 16; ++q) {
        int f = tid + q * 256;          // float4 slot in [0,4096)
        int r  = f >> 6;                // row in tile
        int c4 = f & 63;                // float4 column
        int grow = row0 + r;
        int b = grow >> 11;             // / Tn
        int t = grow & (Tn - 1);
        float4 v = *(const float4*)(in + (long)b * in_bstride + (long)t * Hn + c4 * 4);
        *(float4*)(&a_lds[r][c4 * 4]) = v;
    }
    __syncthreads();

    const int o = tid;                  // output column this thread owns
    float acc[64];
    #pragma unroll
    for (int r = 0; r < 64; ++r) acc[r] = 0.f;

    for (int i4 = 0; i4 < 64; ++i4) {
        float w0 = Wx[(i4 * 4 + 0) * Hn + o];
        float w1 = Wx[(i4 * 4 + 1) * Hn + o];
        float w2 = Wx[(i4 * 4 + 2) * Hn + o];
        float w3 = Wx[(i4 * 4 + 3) * Hn + o];
        #pragma unroll
        for (int r = 0; r < 64; ++r) {
            float4 a = *(const float4*)(&a_lds[r][i4 * 4]);
            acc[r] = fmaf(a.x, w0, acc[r]);
            acc[r] = fmaf(a.y, w1, acc[r]);
            acc[r] = fmaf(a.z, w2, acc[r]);
            acc[r] = fmaf(a.w, w3, acc[r]);
        }
    }

    float bo = bias[o];
    #pragma unroll
    for (int r = 0; r < 64; ++r) {
        Z[(long)(row0 + r) * Hn + o] = acc[r] + bo;
    }
}

// ---------------------------------------------------------------------------
// Phase B: recurrence  h_t = tanh(Z[t] + h_{t-d} @ Wh), per stream (b, r).
// One workgroup per stream, 256 threads; thread o holds Wh column o in VGPRs.
// Writes masked output directly to d_out slice for this layer (which also
// serves as next layer's input: masking commutes — valid positions depend
// only on valid positions).
// ---------------------------------------------------------------------------
__global__ __launch_bounds__(256, 1) void rnn_layer(
    const float* __restrict__ Z,
    const float* __restrict__ Wh,       // [256,256], this layer
    float* __restrict__ out,            // d_out + j*Tn*Hn; batch stride DEPTHn*Tn*Hn
    const int* __restrict__ seq_lens,
    int dilation)
{
    __shared__ __align__(16) float h_lds[256];

    const int o = threadIdx.x;
    const int s = blockIdx.x;           // stream id in [0, Bn*dilation)
    const int b = s / dilation;
    const int r = s % dilation;

    // Wh column o -> 256 VGPRs (loaded once; L2-resident across workgroups).
    float w[256];
    #pragma unroll
    for (int i = 0; i < 256; ++i) w[i] = Wh[i * Hn + o];

    h_lds[o] = 0.f;
    const int L = seq_lens[b];
    __syncthreads();

    const float* zb = Z + (long)b * Tn * Hn;
    float* ob = out + (long)b * (DEPTHn * Tn * Hn);

    float z_next = zb[(long)r * Hn + o];
    for (int t = r; t < Tn; t += dilation) {
        float zc = z_next;
        int tn = t + dilation;
        if (tn < Tn) z_next = zb[(long)tn * Hn + o];   // prefetch next step

        float a0 = zc, a1 = 0.f, a2 = 0.f, a3 = 0.f;
        #pragma unroll
        for (int i4 = 0; i4 < 64; ++i4) {
            float4 hv = *(const float4*)(&h_lds[i4 * 4]);
            a0 = fmaf(hv.x, w[i4 * 4 + 0], a0);
            a1 = fmaf(hv.y, w[i4 * 4 + 1], a1);
            a2 = fmaf(hv.z, w[i4 * 4 + 2], a2);
            a3 = fmaf(hv.w, w[i4 * 4 + 3], a3);
        }
        float hn = tanhf((a0 + a1) + (a2 + a3));

        __syncthreads();                 // all reads of h_lds done
        h_lds[o] = hn;
        __syncthreads();                 // h ready for next step

        ob[(long)t * Hn + o] = (t < L) ? hn : 0.f;   // masked store
    }
}

// ---------------------------------------------------------------------------
extern "C" void kernel_launch(void* const* d_in, const int* in_sizes, int n_in,
                              void* d_out, int out_size, void* d_ws, size_t ws_size,
                              hipStream_t stream) {
    const float* x    = (const float*)d_in[0];   // [B,T,H]
    const float* Wx   = (const float*)d_in[1];   // [4,H,H]
    const float* Wh   = (const float*)d_in[2];   // [4,H,H]
    const float* bias = (const float*)d_in[3];   // [4,H]
    const int*   seq  = (const int*)  d_in[4];   // [B]
    float* out = (float*)d_out;                  // [B,4,T,H]
    float* Z   = (float*)d_ws;                   // [B,T,H] scratch (64 MB)

    for (int j = 0; j < DEPTHn; ++j) {
        const float* in;
        long bstride;
        if (j == 0) { in = x;                          bstride = (long)Tn * Hn; }
        else        { in = out + (long)(j - 1) * Tn * Hn; bstride = (long)DEPTHn * Tn * Hn; }

        hipLaunchKernelGGL(gemm_xw, dim3(Bn * Tn / 64), dim3(256), 0, stream,
                           in, bstride, Wx + (long)j * Hn * Hn, bias + (long)j * Hn, Z);

        int d = 1 << j;
        hipLaunchKernelGGL(rnn_layer, dim3(Bn * d), dim3(256), 0, stream,
                           Z, Wh + (long)j * Hn * Hn, out + (long)j * Tn * Hn, seq, d);
    }
}

// Round 2
// 3984.501 us; speedup vs baseline: 3.3925x; 3.3925x over previous
//
#include <hip/hip_runtime.h>

#define Bn 32
#define Tn 2048
#define Hn 256
#define DEPTHn 4

// ---------------------------------------------------------------------------
// Phase A: Z[b,t,:] = in[b,t,:] @ Wx + bias      (parallel over all B*T rows)
// 32-row tiles, 256 threads, ~60 VGPR -> 4 blocks/CU. Weight prefetch.
// ---------------------------------------------------------------------------
#define ROWS 32
__global__ __launch_bounds__(256, 4) void gemm_xw(
    const float* __restrict__ in, long in_bstride,
    const float* __restrict__ Wx, const float* __restrict__ bias,
    float* __restrict__ Z)
{
    __shared__ __align__(16) float a_lds[ROWS][256];

    const int tid = threadIdx.x;
    const int row0 = blockIdx.x * ROWS;   // global row in [0, B*T)

    // Load A tile (32 rows x 256 cols fp32 = 32 KB) coalesced as float4.
    #pragma unroll
    for (int q = 0; q < ROWS * 64 / 256; ++q) {
        int f = tid + q * 256;            // float4 slot
        int r  = f >> 6;                  // row in tile
        int c4 = f & 63;                  // float4 column
        int grow = row0 + r;
        int b = grow >> 11;               // / Tn
        int t = grow & (Tn - 1);
        float4 v = *(const float4*)(in + (long)b * in_bstride + (long)t * Hn + c4 * 4);
        *(float4*)(&a_lds[r][c4 * 4]) = v;
    }
    __syncthreads();

    const int o = tid;                    // output column this thread owns
    float acc[ROWS];
    #pragma unroll
    for (int r = 0; r < ROWS; ++r) acc[r] = 0.f;

    // double-buffered weight column prefetch
    float wc0 = Wx[0 * Hn + o], wc1 = Wx[1 * Hn + o],
          wc2 = Wx[2 * Hn + o], wc3 = Wx[3 * Hn + o];
    for (int i4 = 0; i4 < 64; ++i4) {
        float wn0, wn1, wn2, wn3;
        if (i4 < 63) {
            wn0 = Wx[(i4 * 4 + 4) * Hn + o];
            wn1 = Wx[(i4 * 4 + 5) * Hn + o];
            wn2 = Wx[(i4 * 4 + 6) * Hn + o];
            wn3 = Wx[(i4 * 4 + 7) * Hn + o];
        }
        #pragma unroll
        for (int r = 0; r < ROWS; ++r) {
            float4 a = *(const float4*)(&a_lds[r][i4 * 4]);   // wave-uniform broadcast
            acc[r] = fmaf(a.x, wc0, acc[r]);
            acc[r] = fmaf(a.y, wc1, acc[r]);
            acc[r] = fmaf(a.z, wc2, acc[r]);
            acc[r] = fmaf(a.w, wc3, acc[r]);
        }
        wc0 = wn0; wc1 = wn1; wc2 = wn2; wc3 = wn3;
    }

    float bo = bias[o];
    #pragma unroll
    for (int r = 0; r < ROWS; ++r) {
        Z[(long)(row0 + r) * Hn + o] = acc[r] + bo;
    }
}

// ---------------------------------------------------------------------------
// Phase B: recurrence  h_t = tanh(Z[t] + h_{t-d} @ Wh), per stream (b, r).
// One 1024-thread workgroup per stream. Thread (o = tid&255, kq = tid>>8)
// holds 64 Wh values in VGPRs (no spill), computes a quarter dot-product
// from a wave-uniform LDS broadcast of h, then kq==0 waves reduce + tanh.
// Masked output written directly to the d_out slice (masking commutes:
// valid positions depend only on valid positions).
// ---------------------------------------------------------------------------
__global__ __launch_bounds__(1024, 4) void rnn_layer(
    const float* __restrict__ Z,
    const float* __restrict__ Wh,       // [256,256], this layer
    float* __restrict__ out,            // d_out + j*Tn*Hn; batch stride DEPTHn*Tn*Hn
    const int* __restrict__ seq_lens,
    int dilation)
{
    __shared__ __align__(16) float h_lds[256];
    __shared__ __align__(16) float psum[3][256];

    const int tid = threadIdx.x;
    const int o  = tid & 255;
    const int kq = tid >> 8;            // 0..3 : which quarter of the K dim
    const int s = blockIdx.x;           // stream id in [0, Bn*dilation)
    const int b = s / dilation;
    const int r = s % dilation;

    // 64 Wh values for (rows kq*64..kq*64+63, column o) -> VGPRs.
    float w[64];
    #pragma unroll
    for (int i = 0; i < 64; ++i) w[i] = Wh[(kq * 64 + i) * Hn + o];

    if (tid < 256) h_lds[tid] = 0.f;
    const int L = seq_lens[b];
    __syncthreads();

    const float* zb = Z + (long)b * Tn * Hn;
    float* ob = out + (long)b * (DEPTHn * Tn * Hn);

    float z_next = (kq == 0) ? zb[(long)r * Hn + o] : 0.f;
    for (int t = r; t < Tn; t += dilation) {
        float zc = z_next;
        int tn = t + dilation;
        if (kq == 0 && tn < Tn) z_next = zb[(long)tn * Hn + o];  // overlaps FMA phase

        // quarter dot-product; h_lds address is wave-uniform -> broadcast reads
        float a0 = 0.f, a1 = 0.f, a2 = 0.f, a3 = 0.f;
        const float4* hp = (const float4*)(&h_lds[kq * 64]);
        #pragma unroll
        for (int i4 = 0; i4 < 16; ++i4) {
            float4 hv = hp[i4];
            a0 = fmaf(hv.x, w[i4 * 4 + 0], a0);
            a1 = fmaf(hv.y, w[i4 * 4 + 1], a1);
            a2 = fmaf(hv.z, w[i4 * 4 + 2], a2);
            a3 = fmaf(hv.w, w[i4 * 4 + 3], a3);
        }
        float p = (a0 + a1) + (a2 + a3);
        if (kq) psum[kq - 1][o] = p;
        __syncthreads();                 // psum ready; all h_lds reads done

        if (kq == 0) {
            float ssum = p + psum[0][o] + psum[1][o] + psum[2][o] + zc;
            // fast tanh: 1 - 2/(e^{2x}+1); correct at +/-inf saturation
            float e = __expf(2.f * ssum);
            float hn = 1.f - 2.f / (e + 1.f);
            h_lds[o] = hn;
            ob[(long)t * Hn + o] = (t < L) ? hn : 0.f;   // masked store
        }
        __syncthreads();                 // h ready for next step
    }
}

// ---------------------------------------------------------------------------
extern "C" void kernel_launch(void* const* d_in, const int* in_sizes, int n_in,
                              void* d_out, int out_size, void* d_ws, size_t ws_size,
                              hipStream_t stream) {
    const float* x    = (const float*)d_in[0];   // [B,T,H]
    const float* Wx   = (const float*)d_in[1];   // [4,H,H]
    const float* Wh   = (const float*)d_in[2];   // [4,H,H]
    const float* bias = (const float*)d_in[3];   // [4,H]
    const int*   seq  = (const int*)  d_in[4];   // [B]
    float* out = (float*)d_out;                  // [B,4,T,H]
    float* Z   = (float*)d_ws;                   // [B,T,H] scratch (64 MB)

    for (int j = 0; j < DEPTHn; ++j) {
        const float* in;
        long bstride;
        if (j == 0) { in = x;                             bstride = (long)Tn * Hn; }
        else        { in = out + (long)(j - 1) * Tn * Hn; bstride = (long)DEPTHn * Tn * Hn; }

        hipLaunchKernelGGL(gemm_xw, dim3(Bn * Tn / ROWS), dim3(256), 0, stream,
                           in, bstride, Wx + (long)j * Hn * Hn, bias + (long)j * Hn, Z);

        int d = 1 << j;
        hipLaunchKernelGGL(rnn_layer, dim3(Bn * d), dim3(1024), 0, stream,
                           Z, Wh + (long)j * Hn * Hn, out + (long)j * Tn * Hn, seq, d);
    }
}

// Round 4
// 3103.858 us; speedup vs baseline: 4.3551x; 1.2837x over previous
//
#include <hip/hip_runtime.h>

#define Bn 32
#define Tn 2048
#define Hn 256
#define DEPTHn 4

typedef _Float16 h2 __attribute__((ext_vector_type(2)));
typedef _Float16 h8 __attribute__((ext_vector_type(8)));

__device__ __forceinline__ h2 pkrtz(float a, float b) {
    return __builtin_bit_cast(h2, __builtin_amdgcn_cvt_pkrtz(a, b));
}

// ---------------------------------------------------------------------------
// Phase A: Z[b,t,:] = in[b,t,:] @ Wx + bias. Register-tiled 8x8 fp32.
// 64 rows x 256 cols per block, 256 threads, a-tile in LDS (pad 264 dwords),
// w streamed from L1/L2 (hot 256 KB).
// ---------------------------------------------------------------------------
#define GR 64
__global__ __launch_bounds__(256, 2) void gemm_xw(
    const float* __restrict__ in, long in_bstride,
    const float* __restrict__ Wx, const float* __restrict__ bias,
    float* __restrict__ Z)
{
    __shared__ __align__(16) float a_lds[GR][264];   // pad: 16B-aligned rows, bank-spread

    const int tid = threadIdx.x;
    const int row0 = blockIdx.x * GR;

    // stage A tile (64 x 256 fp32), coalesced float4
    #pragma unroll
    for (int q = 0; q < 16; ++q) {
        int f = tid + q * 256;
        int r  = f >> 6;
        int c4 = f & 63;
        int grow = row0 + r;
        int b = grow >> 11;              // / Tn
        int t = grow & (Tn - 1);
        float4 v = *(const float4*)(in + (long)b * in_bstride + (long)t * Hn + c4 * 4);
        *(float4*)(&a_lds[r][c4 * 4]) = v;
    }
    __syncthreads();

    const int g  = tid >> 5;             // rows g, g+8, ..., g+56
    const int cg = tid & 31;             // cols cg*8 .. cg*8+7

    float acc[8][8];
    #pragma unroll
    for (int i = 0; i < 8; ++i)
        #pragma unroll
        for (int j = 0; j < 8; ++j) acc[i][j] = 0.f;

    for (int k4 = 0; k4 < 64; ++k4) {
        float4 w[4][2];
        #pragma unroll
        for (int kk = 0; kk < 4; ++kk) {
            const float* wr = Wx + (long)(k4 * 4 + kk) * Hn + cg * 8;
            w[kk][0] = *(const float4*)(wr);
            w[kk][1] = *(const float4*)(wr + 4);
        }
        float4 a[8];
        #pragma unroll
        for (int i = 0; i < 8; ++i)
            a[i] = *(const float4*)(&a_lds[i * 8 + g][k4 * 4]);

        #pragma unroll
        for (int i = 0; i < 8; ++i) {
            #pragma unroll
            for (int kk = 0; kk < 4; ++kk) {
                float av = ((const float*)&a[i])[kk];
                acc[i][0] = fmaf(av, w[kk][0].x, acc[i][0]);
                acc[i][1] = fmaf(av, w[kk][0].y, acc[i][1]);
                acc[i][2] = fmaf(av, w[kk][0].z, acc[i][2]);
                acc[i][3] = fmaf(av, w[kk][0].w, acc[i][3]);
                acc[i][4] = fmaf(av, w[kk][1].x, acc[i][4]);
                acc[i][5] = fmaf(av, w[kk][1].y, acc[i][5]);
                acc[i][6] = fmaf(av, w[kk][1].z, acc[i][6]);
                acc[i][7] = fmaf(av, w[kk][1].w, acc[i][7]);
            }
        }
    }

    float4 b0 = *(const float4*)(bias + cg * 8);
    float4 b1 = *(const float4*)(bias + cg * 8 + 4);
    #pragma unroll
    for (int i = 0; i < 8; ++i) {
        long row = row0 + i * 8 + g;
        float4 o0 = { acc[i][0] + b0.x, acc[i][1] + b0.y, acc[i][2] + b0.z, acc[i][3] + b0.w };
        float4 o1 = { acc[i][4] + b1.x, acc[i][5] + b1.y, acc[i][6] + b1.z, acc[i][7] + b1.w };
        *(float4*)(Z + row * Hn + cg * 8)     = o0;
        *(float4*)(Z + row * Hn + cg * 8 + 4) = o1;
    }
}

// ---------------------------------------------------------------------------
// Phase B: h_t = tanh(Z[t] + h_{t-d} @ Wh) per stream (b, r).
// 1024 threads: wave wv handles channels wv*16..+15; lane (q = lane>>4,
// c = lane&15) computes the k-quarter [64q,64q+64) for channel wv*16+c as
// 32 v_dot2_f32_f16 against packed-f16 h in LDS. Reduce via shfl_xor(16,32),
// tanh redundantly in all lanes, double-buffered h -> ONE barrier per step.
// h LDS layout: pair index m in [0,128), slot = (m>>5)*36 + (m&31) (pad 4
// dwords per quarter -> conflict-free 4-address broadcast b128 reads).
// ---------------------------------------------------------------------------
__global__ __launch_bounds__(1024, 4) void rnn_layer(
    const float* __restrict__ Z,
    const float* __restrict__ Wh,       // [256,256] this layer
    float* __restrict__ out,            // d_out + j*Tn*Hn; batch stride DEPTHn*Tn*Hn
    const int* __restrict__ seq_lens,
    int dilation)
{
    __shared__ __align__(16) h2 hbuf[2 * 144];

    const int tid  = threadIdx.x;
    const int wv   = tid >> 6;
    const int lane = tid & 63;
    const int q    = lane >> 4;
    const int c    = lane & 15;
    const int ch   = wv * 16 + c;

    const int s = blockIdx.x;
    const int b = s / dilation;
    const int r = s % dilation;

    // pack Wh column ch, k-quarter q, as 32 f16 pairs in VGPRs
    h2 w16[32];
    #pragma unroll
    for (int p = 0; p < 32; ++p) {
        float w0 = Wh[(long)(64 * q + 2 * p)     * Hn + ch];
        float w1 = Wh[(long)(64 * q + 2 * p + 1) * Hn + ch];
        w16[p] = pkrtz(w0, w1);
    }

    if (tid < 288) ((unsigned int*)hbuf)[tid] = 0u;
    const int L = seq_lens[b];
    __syncthreads();

    const float* zb = Z + (long)b * Tn * Hn;
    float* ob = out + (long)b * (DEPTHn * Tn * Hn);

    int cur = 0;
    float z_next = zb[(long)r * Hn + ch];
    for (int t = r; t < Tn; t += dilation) {
        float zc = z_next;
        int tn = t + dilation;
        if (tn < Tn) z_next = zb[(long)tn * Hn + ch];   // hides under dot phase

        const h2* hp = &hbuf[cur * 144 + q * 36];
        float a0 = 0.f, a1 = 0.f, a2 = 0.f, a3 = 0.f;
        #pragma unroll
        for (int i4 = 0; i4 < 8; ++i4) {
            h8 hv = *(const h8*)(hp + i4 * 4);           // one ds_read_b128
            h2 p0 = __builtin_shufflevector(hv, hv, 0, 1);
            h2 p1 = __builtin_shufflevector(hv, hv, 2, 3);
            h2 p2 = __builtin_shufflevector(hv, hv, 4, 5);
            h2 p3 = __builtin_shufflevector(hv, hv, 6, 7);
            a0 = __builtin_amdgcn_fdot2(p0, w16[i4 * 4 + 0], a0, false);
            a1 = __builtin_amdgcn_fdot2(p1, w16[i4 * 4 + 1], a1, false);
            a2 = __builtin_amdgcn_fdot2(p2, w16[i4 * 4 + 2], a2, false);
            a3 = __builtin_amdgcn_fdot2(p3, w16[i4 * 4 + 3], a3, false);
        }
        float p = (a0 + a1) + (a2 + a3);
        p += __shfl_xor(p, 16);
        p += __shfl_xor(p, 32);

        float ssum = p + zc;
        float e = __expf(2.f * ssum);                    // saturates correctly at +/-inf
        float hn = 1.f - 2.f / (e + 1.f);

        float ho = __shfl_xor(hn, 1);                    // neighbor channel's h
        if (q == 0) {
            ob[(long)t * Hn + ch] = (t < L) ? hn : 0.f;  // masked store
            if (!(c & 1)) {
                int m = wv * 8 + (c >> 1);               // pair index
                hbuf[(cur ^ 1) * 144 + (m >> 5) * 36 + (m & 31)] = pkrtz(hn, ho);
            }
        }
        __syncthreads();                                  // h[nxt] ready; cur reusable
        cur ^= 1;
    }
}

// ---------------------------------------------------------------------------
extern "C" void kernel_launch(void* const* d_in, const int* in_sizes, int n_in,
                              void* d_out, int out_size, void* d_ws, size_t ws_size,
                              hipStream_t stream) {
    const float* x    = (const float*)d_in[0];   // [B,T,H]
    const float* Wx   = (const float*)d_in[1];   // [4,H,H]
    const float* Wh   = (const float*)d_in[2];   // [4,H,H]
    const float* bias = (const float*)d_in[3];   // [4,H]
    const int*   seq  = (const int*)  d_in[4];   // [B]
    float* out = (float*)d_out;                  // [B,4,T,H]
    float* Z   = (float*)d_ws;                   // [B,T,H] scratch (64 MB)

    for (int j = 0; j < DEPTHn; ++j) {
        const float* in;
        long bstride;
        if (j == 0) { in = x;                             bstride = (long)Tn * Hn; }
        else        { in = out + (long)(j - 1) * Tn * Hn; bstride = (long)DEPTHn * Tn * Hn; }

        hipLaunchKernelGGL(gemm_xw, dim3(Bn * Tn / GR), dim3(256), 0, stream,
                           in, bstride, Wx + (long)j * Hn * Hn, bias + (long)j * Hn, Z);

        int d = 1 << j;
        hipLaunchKernelGGL(rnn_layer, dim3(Bn * d), dim3(1024), 0, stream,
                           Z, Wh + (long)j * Hn * Hn, out + (long)j * Tn * Hn, seq, d);
    }
}

// Round 6
// 2614.851 us; speedup vs baseline: 5.1695x; 1.1870x over previous
//
#include <hip/hip_runtime.h>

#define Bn 32
#define Tn 2048
#define Hn 256
#define DEPTHn 4

typedef _Float16 h2 __attribute__((ext_vector_type(2)));
typedef _Float16 h8 __attribute__((ext_vector_type(8)));

__device__ __forceinline__ h2 pkrtz(float a, float b) {
    return __builtin_bit_cast(h2, __builtin_amdgcn_cvt_pkrtz(a, b));
}

// quad_perm DPP: lane gets value from lane (quad-local) perm. 0xB1 = xor1, 0x4E = xor2.
template <int CTRL>
__device__ __forceinline__ float dpp_qp(float x) {
    int xi = __builtin_bit_cast(int, x);
    int r = __builtin_amdgcn_update_dpp(0, xi, CTRL, 0xF, 0xF, true);
    return __builtin_bit_cast(float, r);
}

// ---------------------------------------------------------------------------
// Phase A: Z[b,t,:] = in[b,t,:] @ Wx + bias. Register-tiled 8x8 fp32.
// (unchanged — known good, ~110 µs per dispatch)
// ---------------------------------------------------------------------------
#define GR 64
__global__ __launch_bounds__(256, 2) void gemm_xw(
    const float* __restrict__ in, long in_bstride,
    const float* __restrict__ Wx, const float* __restrict__ bias,
    float* __restrict__ Z)
{
    __shared__ __align__(16) float a_lds[GR][264];

    const int tid = threadIdx.x;
    const int row0 = blockIdx.x * GR;

    #pragma unroll
    for (int q = 0; q < 16; ++q) {
        int f = tid + q * 256;
        int r  = f >> 6;
        int c4 = f & 63;
        int grow = row0 + r;
        int b = grow >> 11;
        int t = grow & (Tn - 1);
        float4 v = *(const float4*)(in + (long)b * in_bstride + (long)t * Hn + c4 * 4);
        *(float4*)(&a_lds[r][c4 * 4]) = v;
    }
    __syncthreads();

    const int g  = tid >> 5;
    const int cg = tid & 31;

    float acc[8][8];
    #pragma unroll
    for (int i = 0; i < 8; ++i)
        #pragma unroll
        for (int j = 0; j < 8; ++j) acc[i][j] = 0.f;

    for (int k4 = 0; k4 < 64; ++k4) {
        float4 w[4][2];
        #pragma unroll
        for (int kk = 0; kk < 4; ++kk) {
            const float* wr = Wx + (long)(k4 * 4 + kk) * Hn + cg * 8;
            w[kk][0] = *(const float4*)(wr);
            w[kk][1] = *(const float4*)(wr + 4);
        }
        float4 a[8];
        #pragma unroll
        for (int i = 0; i < 8; ++i)
            a[i] = *(const float4*)(&a_lds[i * 8 + g][k4 * 4]);

        #pragma unroll
        for (int i = 0; i < 8; ++i) {
            #pragma unroll
            for (int kk = 0; kk < 4; ++kk) {
                float av = ((const float*)&a[i])[kk];
                acc[i][0] = fmaf(av, w[kk][0].x, acc[i][0]);
                acc[i][1] = fmaf(av, w[kk][0].y, acc[i][1]);
                acc[i][2] = fmaf(av, w[kk][0].z, acc[i][2]);
                acc[i][3] = fmaf(av, w[kk][0].w, acc[i][3]);
                acc[i][4] = fmaf(av, w[kk][1].x, acc[i][4]);
                acc[i][5] = fmaf(av, w[kk][1].y, acc[i][5]);
                acc[i][6] = fmaf(av, w[kk][1].z, acc[i][6]);
                acc[i][7] = fmaf(av, w[kk][1].w, acc[i][7]);
            }
        }
    }

    float4 b0 = *(const float4*)(bias + cg * 8);
    float4 b1 = *(const float4*)(bias + cg * 8 + 4);
    #pragma unroll
    for (int i = 0; i < 8; ++i) {
        long row = row0 + i * 8 + g;
        float4 o0 = { acc[i][0] + b0.x, acc[i][1] + b0.y, acc[i][2] + b0.z, acc[i][3] + b0.w };
        float4 o1 = { acc[i][4] + b1.x, acc[i][5] + b1.y, acc[i][6] + b1.z, acc[i][7] + b1.w };
        *(float4*)(Z + row * Hn + cg * 8)     = o0;
        *(float4*)(Z + row * Hn + cg * 8 + 4) = o1;
    }
}

// ---------------------------------------------------------------------------
// Phase B: h_t = tanh(Z[t] + h_{t-d} @ Wh) per stream (b, r).
// 512 threads = 8 waves. Lane (q = lane&3, c = lane>>2) of wave wv owns TWO
// channels ch0 = wv*32+c, ch1 = ch0+16 and computes their k-quarter
// [64q, 64q+64) dots vs the same h chunk. q is in the LOW lane bits so the
// k-reduce is two quad_perm DPP folds (pure VALU, no DS, no permlane).
// LDS layout: pair m -> slot (m>>5)*36 + (m&31); the 36-dword quarter stride
// puts the quad's 4 addresses on disjoint banks (conflict-free broadcast).
// Sync: ONE fused asm "s_waitcnt lgkmcnt(0); s_barrier" with memory clobber —
// LDS-only drain, compiler cannot move any memory op across the barrier,
// z prefetch loads and output stores stay in flight.
// ---------------------------------------------------------------------------
__global__ __launch_bounds__(512) void rnn_layer(
    const float* __restrict__ Z,
    const float* __restrict__ Wh,       // [256,256] this layer
    float* __restrict__ out,            // d_out + j*Tn*Hn; batch stride DEPTHn*Tn*Hn
    const int* __restrict__ seq_lens,
    int dilation)
{
    __shared__ __align__(16) h2 hbuf[2 * 144];

    const int tid  = threadIdx.x;
    const int wv   = tid >> 6;          // 0..7
    const int lane = tid & 63;
    const int q    = lane & 3;          // k-quarter (low bits -> quad DPP reduce)
    const int c    = lane >> 2;         // 0..15
    const int ch0  = wv * 32 + c;
    const int ch1  = ch0 + 16;

    const int s = blockIdx.x;
    const int b = s / dilation;
    const int r = s % dilation;

    // Wh columns ch0, ch1 for k-quarter q, packed f16 pairs -> 64 VGPR
    h2 wA[32], wB[32];
    #pragma unroll
    for (int p = 0; p < 32; ++p) {
        int k0 = 64 * q + 2 * p;
        wA[p] = pkrtz(Wh[(long)k0 * Hn + ch0], Wh[(long)(k0 + 1) * Hn + ch0]);
        wB[p] = pkrtz(Wh[(long)k0 * Hn + ch1], Wh[(long)(k0 + 1) * Hn + ch1]);
    }

    if (tid < 288) ((unsigned int*)hbuf)[tid] = 0u;
    const int L = seq_lens[b];
    __syncthreads();

    const float* zb = Z + (long)b * Tn * Hn;
    float* ob = out + (long)b * (DEPTHn * Tn * Hn);

    const int och = (q & 1) ? ch1 : ch0;   // this lane's produced channel
    const bool producer = (q < 2);

    int cur = 0;
    float z1 = 0.f, z2 = 0.f;
    if (producer) {
        z1 = zb[(long)r * Hn + och];
        if (r + dilation < Tn) z2 = zb[(long)(r + dilation) * Hn + och];
    }

    for (int t = r; t < Tn; t += dilation) {
        float zc = z1;
        z1 = z2;
        int t2 = t + 2 * dilation;
        if (producer && t2 < Tn) z2 = zb[(long)t2 * Hn + och];  // depth-2 prefetch

        const h2* hp = &hbuf[cur * 144 + q * 36];
        float a0 = 0.f, a1 = 0.f, a2 = 0.f, a3 = 0.f;
        float b0 = 0.f, b1 = 0.f, b2 = 0.f, b3 = 0.f;
        #pragma unroll
        for (int i4 = 0; i4 < 8; ++i4) {
            h8 hv = *(const h8*)(hp + i4 * 4);               // ds_read_b128 bcast
            h2 p0 = __builtin_shufflevector(hv, hv, 0, 1);
            h2 p1 = __builtin_shufflevector(hv, hv, 2, 3);
            h2 p2 = __builtin_shufflevector(hv, hv, 4, 5);
            h2 p3 = __builtin_shufflevector(hv, hv, 6, 7);
            a0 = __builtin_amdgcn_fdot2(p0, wA[i4 * 4 + 0], a0, false);
            a1 = __builtin_amdgcn_fdot2(p1, wA[i4 * 4 + 1], a1, false);
            a2 = __builtin_amdgcn_fdot2(p2, wA[i4 * 4 + 2], a2, false);
            a3 = __builtin_amdgcn_fdot2(p3, wA[i4 * 4 + 3], a3, false);
            b0 = __builtin_amdgcn_fdot2(p0, wB[i4 * 4 + 0], b0, false);
            b1 = __builtin_amdgcn_fdot2(p1, wB[i4 * 4 + 1], b1, false);
            b2 = __builtin_amdgcn_fdot2(p2, wB[i4 * 4 + 2], b2, false);
            b3 = __builtin_amdgcn_fdot2(p3, wB[i4 * 4 + 3], b3, false);
        }
        float pA = (a0 + a1) + (a2 + a3);
        float pB = (b0 + b1) + (b2 + b3);

        // k-quarter reduce across the quad: xor1 then xor2, pure VALU DPP
        pA += dpp_qp<0xB1>(pA);
        pA += dpp_qp<0x4E>(pA);
        pB += dpp_qp<0xB1>(pB);
        pB += dpp_qp<0x4E>(pB);

        if (producer) {
            float ssum = ((q & 1) ? pB : pA) + zc;
            float e = __expf(2.f * ssum);                    // saturates at +/-inf
            float hn = 1.f - 2.f / (e + 1.f);
            ob[(long)t * Hn + och] = (t < L) ? hn : 0.f;     // masked store (in flight)
            int m = och >> 1;
            _Float16* hw = (_Float16*)&hbuf[(cur ^ 1) * 144 + (m >> 5) * 36 + (m & 31)];
            hw[och & 1] = (_Float16)hn;                      // ds_write_b16
        }

        // fused LDS-drain + barrier: one opaque memory op, nothing crosses it
        asm volatile("s_waitcnt lgkmcnt(0)\n\ts_barrier" ::: "memory");
        cur ^= 1;
    }
}

// ---------------------------------------------------------------------------
extern "C" void kernel_launch(void* const* d_in, const int* in_sizes, int n_in,
                              void* d_out, int out_size, void* d_ws, size_t ws_size,
                              hipStream_t stream) {
    const float* x    = (const float*)d_in[0];   // [B,T,H]
    const float* Wx   = (const float*)d_in[1];   // [4,H,H]
    const float* Wh   = (const float*)d_in[2];   // [4,H,H]
    const float* bias = (const float*)d_in[3];   // [4,H]
    const int*   seq  = (const int*)  d_in[4];   // [B]
    float* out = (float*)d_out;                  // [B,4,T,H]
    float* Z   = (float*)d_ws;                   // [B,T,H] scratch (64 MB)

    for (int j = 0; j < DEPTHn; ++j) {
        const float* in;
        long bstride;
        if (j == 0) { in = x;                             bstride = (long)Tn * Hn; }
        else        { in = out + (long)(j - 1) * Tn * Hn; bstride = (long)DEPTHn * Tn * Hn; }

        hipLaunchKernelGGL(gemm_xw, dim3(Bn * Tn / GR), dim3(256), 0, stream,
                           in, bstride, Wx + (long)j * Hn * Hn, bias + (long)j * Hn, Z);

        int d = 1 << j;
        hipLaunchKernelGGL(rnn_layer, dim3(Bn * d), dim3(512), 0, stream,
                           Z, Wh + (long)j * Hn * Hn, out + (long)j * Tn * Hn, seq, d);
    }
}

// Round 7
// 2496.598 us; speedup vs baseline: 5.4144x; 1.0474x over previous
//
#include <hip/hip_runtime.h>

#define Bn 32
#define Tn 2048
#define Hn 256
#define DEPTHn 4

typedef _Float16 h2 __attribute__((ext_vector_type(2)));
typedef _Float16 h8 __attribute__((ext_vector_type(8)));

__device__ __forceinline__ h2 pkrtz(float a, float b) {
    return __builtin_bit_cast(h2, __builtin_amdgcn_cvt_pkrtz(a, b));
}

// quad_perm DPP: 0xB1 = xor1 [1,0,3,2], 0x4E = xor2 [2,3,0,1]
template <int CTRL>
__device__ __forceinline__ float dpp_qp(float x) {
    int xi = __builtin_bit_cast(int, x);
    int r = __builtin_amdgcn_update_dpp(0, xi, CTRL, 0xF, 0xF, true);
    return __builtin_bit_cast(float, r);
}

// ---------------------------------------------------------------------------
// Phase A: Z[b,t,:] = in[b,t,:] @ Wx + bias. Register-tiled 8x8 fp32.
// (unchanged — known good, ~110 µs per dispatch)
// ---------------------------------------------------------------------------
#define GR 64
__global__ __launch_bounds__(256, 2) void gemm_xw(
    const float* __restrict__ in, long in_bstride,
    const float* __restrict__ Wx, const float* __restrict__ bias,
    float* __restrict__ Z)
{
    __shared__ __align__(16) float a_lds[GR][264];

    const int tid = threadIdx.x;
    const int row0 = blockIdx.x * GR;

    #pragma unroll
    for (int q = 0; q < 16; ++q) {
        int f = tid + q * 256;
        int r  = f >> 6;
        int c4 = f & 63;
        int grow = row0 + r;
        int b = grow >> 11;
        int t = grow & (Tn - 1);
        float4 v = *(const float4*)(in + (long)b * in_bstride + (long)t * Hn + c4 * 4);
        *(float4*)(&a_lds[r][c4 * 4]) = v;
    }
    __syncthreads();

    const int g  = tid >> 5;
    const int cg = tid & 31;

    float acc[8][8];
    #pragma unroll
    for (int i = 0; i < 8; ++i)
        #pragma unroll
        for (int j = 0; j < 8; ++j) acc[i][j] = 0.f;

    for (int k4 = 0; k4 < 64; ++k4) {
        float4 w[4][2];
        #pragma unroll
        for (int kk = 0; kk < 4; ++kk) {
            const float* wr = Wx + (long)(k4 * 4 + kk) * Hn + cg * 8;
            w[kk][0] = *(const float4*)(wr);
            w[kk][1] = *(const float4*)(wr + 4);
        }
        float4 a[8];
        #pragma unroll
        for (int i = 0; i < 8; ++i)
            a[i] = *(const float4*)(&a_lds[i * 8 + g][k4 * 4]);

        #pragma unroll
        for (int i = 0; i < 8; ++i) {
            #pragma unroll
            for (int kk = 0; kk < 4; ++kk) {
                float av = ((const float*)&a[i])[kk];
                acc[i][0] = fmaf(av, w[kk][0].x, acc[i][0]);
                acc[i][1] = fmaf(av, w[kk][0].y, acc[i][1]);
                acc[i][2] = fmaf(av, w[kk][0].z, acc[i][2]);
                acc[i][3] = fmaf(av, w[kk][0].w, acc[i][3]);
                acc[i][4] = fmaf(av, w[kk][1].x, acc[i][4]);
                acc[i][5] = fmaf(av, w[kk][1].y, acc[i][5]);
                acc[i][6] = fmaf(av, w[kk][1].z, acc[i][6]);
                acc[i][7] = fmaf(av, w[kk][1].w, acc[i][7]);
            }
        }
    }

    float4 b0 = *(const float4*)(bias + cg * 8);
    float4 b1 = *(const float4*)(bias + cg * 8 + 4);
    #pragma unroll
    for (int i = 0; i < 8; ++i) {
        long row = row0 + i * 8 + g;
        float4 o0 = { acc[i][0] + b0.x, acc[i][1] + b0.y, acc[i][2] + b0.z, acc[i][3] + b0.w };
        float4 o1 = { acc[i][4] + b1.x, acc[i][5] + b1.y, acc[i][6] + b1.z, acc[i][7] + b1.w };
        *(float4*)(Z + row * Hn + cg * 8)     = o0;
        *(float4*)(Z + row * Hn + cg * 8 + 4) = o1;
    }
}

// ---------------------------------------------------------------------------
// Phase B: h_t = tanh(Z[t] + h_{t-d} @ Wh) per stream (b, r).
// 256 threads = 4 waves (1/SIMD). Lane (q = lane&3, c = lane>>2) of wave wv
// owns FOUR channels ch_i = wv*64 + 16*i + c (i=0..3), all sharing the same
// k-quarter [64q, 64q+64) broadcast h chunk -> per step only 8 ds_read_b128
// per wave (32 total, half of R6's 64+). k-reduce = 2 quad_perm DPP folds per
// channel (pure VALU). Every lane produces channel och = wv*64 + 16*q + c:
// exp/tanh, coalesced masked global store, one ds_write_b16 per wave.
// Sync: fused "s_waitcnt lgkmcnt(0); s_barrier" asm (LDS-only drain; z
// prefetch loads and output stores stay in flight across steps).
// ---------------------------------------------------------------------------
__global__ __launch_bounds__(256) void rnn_layer(
    const float* __restrict__ Z,
    const float* __restrict__ Wh,       // [256,256] this layer
    float* __restrict__ out,            // d_out + j*Tn*Hn; batch stride DEPTHn*Tn*Hn
    const int* __restrict__ seq_lens,
    int dilation)
{
    __shared__ __align__(16) h2 hbuf[2 * 144];

    const int tid  = threadIdx.x;
    const int wv   = tid >> 6;          // 0..3
    const int lane = tid & 63;
    const int q    = lane & 3;          // k-quarter (low bits -> quad DPP reduce)
    const int c    = lane >> 2;         // 0..15
    const int ch0  = wv * 64 + c;       // + 16*i for i = 0..3

    const int s = blockIdx.x;
    const int b = s / dilation;
    const int r = s % dilation;

    // Wh columns ch0..ch0+48 for k-quarter q, packed f16 pairs -> 128 VGPR
    h2 w0[32], w1[32], w2[32], w3[32];
    #pragma unroll
    for (int p = 0; p < 32; ++p) {
        int k0 = 64 * q + 2 * p;
        const float* wr0 = Wh + (long)k0 * Hn;
        const float* wr1 = Wh + (long)(k0 + 1) * Hn;
        w0[p] = pkrtz(wr0[ch0],      wr1[ch0]);
        w1[p] = pkrtz(wr0[ch0 + 16], wr1[ch0 + 16]);
        w2[p] = pkrtz(wr0[ch0 + 32], wr1[ch0 + 32]);
        w3[p] = pkrtz(wr0[ch0 + 48], wr1[ch0 + 48]);
    }

    ((unsigned int*)hbuf)[tid] = 0u;
    if (tid < 32) ((unsigned int*)hbuf)[256 + tid] = 0u;
    const int L = seq_lens[b];
    __syncthreads();

    const float* zb = Z + (long)b * Tn * Hn;
    float* ob = out + (long)b * (DEPTHn * Tn * Hn);

    const int och = ch0 + 16 * q;       // this lane's produced channel

    int cur = 0;
    float z1 = zb[(long)r * Hn + och];
    float z2 = 0.f;
    if (r + dilation < Tn) z2 = zb[(long)(r + dilation) * Hn + och];

    for (int t = r; t < Tn; t += dilation) {
        float zc = z1;
        z1 = z2;
        int t2 = t + 2 * dilation;
        if (t2 < Tn) z2 = zb[(long)t2 * Hn + och];   // depth-2 prefetch

        const h2* hp = &hbuf[cur * 144 + q * 36];
        float s0a = 0.f, s0b = 0.f, s1a = 0.f, s1b = 0.f;
        float s2a = 0.f, s2b = 0.f, s3a = 0.f, s3b = 0.f;
        #pragma unroll
        for (int i4 = 0; i4 < 8; ++i4) {
            h8 hv = *(const h8*)(hp + i4 * 4);       // ds_read_b128 bcast
            h2 p0 = __builtin_shufflevector(hv, hv, 0, 1);
            h2 p1 = __builtin_shufflevector(hv, hv, 2, 3);
            h2 p2 = __builtin_shufflevector(hv, hv, 4, 5);
            h2 p3 = __builtin_shufflevector(hv, hv, 6, 7);
            s0a = __builtin_amdgcn_fdot2(p0, w0[i4 * 4 + 0], s0a, false);
            s0b = __builtin_amdgcn_fdot2(p1, w0[i4 * 4 + 1], s0b, false);
            s0a = __builtin_amdgcn_fdot2(p2, w0[i4 * 4 + 2], s0a, false);
            s0b = __builtin_amdgcn_fdot2(p3, w0[i4 * 4 + 3], s0b, false);
            s1a = __builtin_amdgcn_fdot2(p0, w1[i4 * 4 + 0], s1a, false);
            s1b = __builtin_amdgcn_fdot2(p1, w1[i4 * 4 + 1], s1b, false);
            s1a = __builtin_amdgcn_fdot2(p2, w1[i4 * 4 + 2], s1a, false);
            s1b = __builtin_amdgcn_fdot2(p3, w1[i4 * 4 + 3], s1b, false);
            s2a = __builtin_amdgcn_fdot2(p0, w2[i4 * 4 + 0], s2a, false);
            s2b = __builtin_amdgcn_fdot2(p1, w2[i4 * 4 + 1], s2b, false);
            s2a = __builtin_amdgcn_fdot2(p2, w2[i4 * 4 + 2], s2a, false);
            s2b = __builtin_amdgcn_fdot2(p3, w2[i4 * 4 + 3], s2b, false);
            s3a = __builtin_amdgcn_fdot2(p0, w3[i4 * 4 + 0], s3a, false);
            s3b = __builtin_amdgcn_fdot2(p1, w3[i4 * 4 + 1], s3b, false);
            s3a = __builtin_amdgcn_fdot2(p2, w3[i4 * 4 + 2], s3a, false);
            s3b = __builtin_amdgcn_fdot2(p3, w3[i4 * 4 + 3], s3b, false);
        }
        float s0 = s0a + s0b;
        float s1 = s1a + s1b;
        float s2 = s2a + s2b;
        float s3 = s3a + s3b;

        // quad-local k reduce: xor1 then xor2, pure VALU DPP
        s0 += dpp_qp<0xB1>(s0);  s0 += dpp_qp<0x4E>(s0);
        s1 += dpp_qp<0xB1>(s1);  s1 += dpp_qp<0x4E>(s1);
        s2 += dpp_qp<0xB1>(s2);  s2 += dpp_qp<0x4E>(s2);
        s3 += dpp_qp<0xB1>(s3);  s3 += dpp_qp<0x4E>(s3);

        // lane produces channel i == q
        float se = (q & 2) ? ((q & 1) ? s3 : s2) : ((q & 1) ? s1 : s0);

        float ssum = se + zc;
        float e = __expf(2.f * ssum);                // saturates at +/-inf
        float hn = 1.f - 2.f / (e + 1.f);
        ob[(long)t * Hn + och] = (t < L) ? hn : 0.f; // coalesced, stays in flight

        int m = och >> 1;
        _Float16* hw = (_Float16*)&hbuf[(cur ^ 1) * 144 + (m >> 5) * 36 + (m & 31)];
        hw[och & 1] = (_Float16)hn;                  // ds_write_b16

        // fused LDS-drain + barrier: one opaque memory op, nothing crosses it
        asm volatile("s_waitcnt lgkmcnt(0)\n\ts_barrier" ::: "memory");
        cur ^= 1;
    }
}

// ---------------------------------------------------------------------------
extern "C" void kernel_launch(void* const* d_in, const int* in_sizes, int n_in,
                              void* d_out, int out_size, void* d_ws, size_t ws_size,
                              hipStream_t stream) {
    const float* x    = (const float*)d_in[0];   // [B,T,H]
    const float* Wx   = (const float*)d_in[1];   // [4,H,H]
    const float* Wh   = (const float*)d_in[2];   // [4,H,H]
    const float* bias = (const float*)d_in[3];   // [4,H]
    const int*   seq  = (const int*)  d_in[4];   // [B]
    float* out = (float*)d_out;                  // [B,4,T,H]
    float* Z   = (float*)d_ws;                   // [B,T,H] scratch (64 MB)

    for (int j = 0; j < DEPTHn; ++j) {
        const float* in;
        long bstride;
        if (j == 0) { in = x;                             bstride = (long)Tn * Hn; }
        else        { in = out + (long)(j - 1) * Tn * Hn; bstride = (long)DEPTHn * Tn * Hn; }

        hipLaunchKernelGGL(gemm_xw, dim3(Bn * Tn / GR), dim3(256), 0, stream,
                           in, bstride, Wx + (long)j * Hn * Hn, bias + (long)j * Hn, Z);

        int d = 1 << j;
        hipLaunchKernelGGL(rnn_layer, dim3(Bn * d), dim3(256), 0, stream,
                           Z, Wh + (long)j * Hn * Hn, out + (long)j * Tn * Hn, seq, d);
    }
}